// Round 1
// baseline (815.334 us; speedup 1.0000x reference)
//
#include <hip/hip_runtime.h>
#include <math.h>

#define DIM 128
#define NHEADS 16
#define DPH 8
#define NATOMS 50000
#define NEDGES 400000
#define LN_EPS 1e-5f

// ---------------------------------------------------------------------------
// K1: fused LayerNorm + QKV projection.
// Block = 256 threads handles 16 atoms. h (normalized) staged in LDS.
// Thread t: cpart = t&127 (col within 128-group), agrp = t>>7 (atom half).
// Each thread accumulates 8 atoms x 3 col-groups = 24 outputs.
// ---------------------------------------------------------------------------
__global__ __launch_bounds__(256) void k_ln_qkv(
    const float* __restrict__ node, const float* __restrict__ w,
    const float* __restrict__ bias, const float* __restrict__ g,
    const float* __restrict__ beta, float* __restrict__ qkv)
{
  __shared__ float h[16][DIM];
  const int a0 = blockIdx.x * 16;
  const int tid = threadIdx.x;
  const int wid = tid >> 6;
  const int lane = tid & 63;

  // LayerNorm: wave `wid` handles atoms wid*4 .. wid*4+3 (2 elems per lane)
  for (int j = 0; j < 4; ++j) {
    const int a = wid * 4 + j;
    const float x0 = node[(a0 + a) * DIM + lane];
    const float x1 = node[(a0 + a) * DIM + 64 + lane];
    float s = x0 + x1;
    #pragma unroll
    for (int m = 1; m < 64; m <<= 1) s += __shfl_xor(s, m);
    const float mu = s * (1.0f / 128.0f);
    const float d0 = x0 - mu, d1 = x1 - mu;
    float v = d0 * d0 + d1 * d1;
    #pragma unroll
    for (int m = 1; m < 64; m <<= 1) v += __shfl_xor(v, m);
    const float rs = rsqrtf(v * (1.0f / 128.0f) + LN_EPS);
    h[a][lane]      = d0 * rs * g[lane]      + beta[lane];
    h[a][64 + lane] = d1 * rs * g[64 + lane] + beta[64 + lane];
  }
  __syncthreads();

  const int cpart = tid & 127;
  const int agrp = tid >> 7;  // 0 or 1

  float acc[8][3];
  const float b0 = bias[cpart];
  const float b1 = bias[cpart + 128];
  const float b2 = bias[cpart + 256];
  #pragma unroll
  for (int j = 0; j < 8; ++j) { acc[j][0] = b0; acc[j][1] = b1; acc[j][2] = b2; }

  #pragma unroll 4
  for (int k = 0; k < DIM; ++k) {
    const float w0 = w[k * 384 + cpart];
    const float w1 = w[k * 384 + cpart + 128];
    const float w2 = w[k * 384 + cpart + 256];
    #pragma unroll
    for (int j = 0; j < 8; ++j) {
      const float hk = h[agrp * 8 + j][k];
      acc[j][0] = fmaf(hk, w0, acc[j][0]);
      acc[j][1] = fmaf(hk, w1, acc[j][1]);
      acc[j][2] = fmaf(hk, w2, acc[j][2]);
    }
  }

  #pragma unroll
  for (int j = 0; j < 8; ++j) {
    const int atom = a0 + agrp * 8 + j;
    qkv[atom * 384 + cpart]       = acc[j][0];
    qkv[atom * 384 + cpart + 128] = acc[j][1];
    qkv[atom * 384 + cpart + 256] = acc[j][2];
  }
}

// ---------------------------------------------------------------------------
// K2: per-edge attention + scatter.
// 128 threads per edge (one per output channel). Head = c>>3, lane-in-head =
// c&7. 8-wide shfl_xor reduction for the q.k dot. 4 atomicAdds per thread:
// one into m_feat workspace, three into the m_vec output region.
// ---------------------------------------------------------------------------
__global__ __launch_bounds__(256) void k_edge(
    const float* __restrict__ qkv, const float* __restrict__ ef,
    const float* __restrict__ evec, const float* __restrict__ radial,
    const int* __restrict__ row, const int* __restrict__ col,
    float* __restrict__ mfeat, float* __restrict__ outvec)
{
  const int tid = blockIdx.x * 256 + threadIdx.x;
  const int e = tid >> 7;
  if (e >= NEDGES) return;
  const int c = tid & 127;
  const int hh = c >> 3;
  const int l8 = c & 7;

  const int r = row[e];
  const int cl = col[e];

  const float* qrow = qkv + r * 384 + hh * 24;
  const float* krow = qkv + cl * 384 + hh * 24;
  const float qv = qrow[l8];
  const float kv = krow[8 + l8];
  const float vv = krow[16 + l8];

  float p = qv * kv;
  p += __shfl_xor(p, 1);
  p += __shfl_xor(p, 2);
  p += __shfl_xor(p, 4);
  // exact GELU: 0.5*x*(1+erf(x/sqrt(2))), then * radial
  const float attn = 0.5f * p * (1.0f + erff(p * 0.70710678118654752f)) * radial[e];

  const float fe = ef[e * 128 + c];
  atomicAdd(&mfeat[r * 128 + c], vv * fe * attn);

  const float e0 = evec[e * 3 + 0];
  const float e1 = evec[e * 3 + 1];
  const float e2 = evec[e * 3 + 2];
  float* ov = outvec + r * 384;
  atomicAdd(&ov[c],       vv * e0);
  atomicAdd(&ov[128 + c], vv * e1);
  atomicAdd(&ov[256 + c], vv * e2);
}

// ---------------------------------------------------------------------------
// K3: delta_node_feat = m_feat @ out_w + out_b.
// Block = 256 threads handles 16 atoms; m tile staged in LDS.
// ---------------------------------------------------------------------------
__global__ __launch_bounds__(256) void k_out(
    const float* __restrict__ mfeat, const float* __restrict__ w,
    const float* __restrict__ bias, float* __restrict__ out)
{
  __shared__ float m[16][DIM];
  const int a0 = blockIdx.x * 16;
  const int tid = threadIdx.x;

  #pragma unroll
  for (int i = 0; i < 8; ++i) {
    const int idx = tid + i * 256;
    m[idx >> 7][idx & 127] = mfeat[a0 * 128 + idx];
  }
  __syncthreads();

  const int cpart = tid & 127;
  const int agrp = tid >> 7;

  float acc[8];
  const float b0 = bias[cpart];
  #pragma unroll
  for (int j = 0; j < 8; ++j) acc[j] = b0;

  #pragma unroll 4
  for (int k = 0; k < DIM; ++k) {
    const float wk = w[k * 128 + cpart];
    #pragma unroll
    for (int j = 0; j < 8; ++j)
      acc[j] = fmaf(m[agrp * 8 + j][k], wk, acc[j]);
  }

  #pragma unroll
  for (int j = 0; j < 8; ++j)
    out[(a0 + agrp * 8 + j) * 128 + cpart] = acc[j];
}

extern "C" void kernel_launch(void* const* d_in, const int* in_sizes, int n_in,
                              void* d_out, int out_size, void* d_ws, size_t ws_size,
                              hipStream_t stream) {
  const float* node_feat = (const float*)d_in[0];
  const float* edge_feat = (const float*)d_in[1];
  const float* edge_vec  = (const float*)d_in[2];
  const float* radial    = (const float*)d_in[3];
  const float* qkv_w     = (const float*)d_in[4];
  const float* qkv_b     = (const float*)d_in[5];
  const float* out_w     = (const float*)d_in[6];
  const float* out_b     = (const float*)d_in[7];
  const float* ln_g      = (const float*)d_in[8];
  const float* ln_b      = (const float*)d_in[9];
  const int*   row       = (const int*)d_in[10];
  const int*   col       = (const int*)d_in[11];

  float* out      = (float*)d_out;
  float* out_feat = out;                           // [50000][128]
  float* out_vec  = out + (size_t)NATOMS * DIM;    // [50000][3][128]

  // workspace: qkv (50000*384 f32 = 76.8MB) + m_feat (50000*128 f32 = 25.6MB)
  float* qkv   = (float*)d_ws;
  float* mfeat = qkv + (size_t)NATOMS * 384;

  hipMemsetAsync(mfeat, 0, (size_t)NATOMS * DIM * sizeof(float), stream);
  hipMemsetAsync(out_vec, 0, (size_t)NATOMS * 3 * DIM * sizeof(float), stream);

  k_ln_qkv<<<NATOMS / 16, 256, 0, stream>>>(node_feat, qkv_w, qkv_b, ln_g, ln_b, qkv);

  const int edge_blocks = (NEDGES * 128) / 256;  // 200000
  k_edge<<<edge_blocks, 256, 0, stream>>>(qkv, edge_feat, edge_vec, radial,
                                          row, col, mfeat, out_vec);

  k_out<<<NATOMS / 16, 256, 0, stream>>>(mfeat, out_w, out_b, out_feat);
}

// Round 2
// 496.540 us; speedup vs baseline: 1.6420x; 1.6420x over previous
//
#include <hip/hip_runtime.h>
#include <math.h>

#define DIM 128
#define NHEADS 16
#define DPH 8
#define NATOMS 50000
#define NEDGES 400000
#define LN_EPS 1e-5f

// ---------------------------------------------------------------------------
// K1: fused LayerNorm + QKV projection.
// Block = 256 threads handles 16 atoms. h (normalized) staged in LDS.
// Writes q into qarr[atom][128] (channel-major: head*8+elem) and k,v into
// kvarr[atom][256] (head*16 + elem for k, head*16+8+elem for v) so the
// per-edge col-gather reads fully-dense cachelines.
// ---------------------------------------------------------------------------
__global__ __launch_bounds__(256) void k_ln_qkv(
    const float* __restrict__ node, const float* __restrict__ w,
    const float* __restrict__ bias, const float* __restrict__ g,
    const float* __restrict__ beta, float* __restrict__ qarr,
    float* __restrict__ kvarr)
{
  __shared__ float h[16][DIM];
  const int a0 = blockIdx.x * 16;
  const int tid = threadIdx.x;
  const int wid = tid >> 6;
  const int lane = tid & 63;

  for (int j = 0; j < 4; ++j) {
    const int a = wid * 4 + j;
    const float x0 = node[(a0 + a) * DIM + lane];
    const float x1 = node[(a0 + a) * DIM + 64 + lane];
    float s = x0 + x1;
    #pragma unroll
    for (int m = 1; m < 64; m <<= 1) s += __shfl_xor(s, m);
    const float mu = s * (1.0f / 128.0f);
    const float d0 = x0 - mu, d1 = x1 - mu;
    float v = d0 * d0 + d1 * d1;
    #pragma unroll
    for (int m = 1; m < 64; m <<= 1) v += __shfl_xor(v, m);
    const float rs = rsqrtf(v * (1.0f / 128.0f) + LN_EPS);
    h[a][lane]      = d0 * rs * g[lane]      + beta[lane];
    h[a][64 + lane] = d1 * rs * g[64 + lane] + beta[64 + lane];
  }
  __syncthreads();

  const int cpart = tid & 127;
  const int agrp = tid >> 7;  // 0 or 1

  float acc[8][3];
  const float b0 = bias[cpart];
  const float b1 = bias[cpart + 128];
  const float b2 = bias[cpart + 256];
  #pragma unroll
  for (int j = 0; j < 8; ++j) { acc[j][0] = b0; acc[j][1] = b1; acc[j][2] = b2; }

  #pragma unroll 4
  for (int k = 0; k < DIM; ++k) {
    const float w0 = w[k * 384 + cpart];
    const float w1 = w[k * 384 + cpart + 128];
    const float w2 = w[k * 384 + cpart + 256];
    #pragma unroll
    for (int j = 0; j < 8; ++j) {
      const float hk = h[agrp * 8 + j][k];
      acc[j][0] = fmaf(hk, w0, acc[j][0]);
      acc[j][1] = fmaf(hk, w1, acc[j][1]);
      acc[j][2] = fmaf(hk, w2, acc[j][2]);
    }
  }

  // Column cpart + part*128 maps to head hj = col/24, off = col%24.
  // off<8 -> q channel hj*8+off ; off in 8..23 -> kv offset hj*16 + off-8.
  int isQ[3], doff[3];
  #pragma unroll
  for (int p = 0; p < 3; ++p) {
    const int colIdx = cpart + p * 128;
    const int hj = colIdx / 24;
    const int off = colIdx - hj * 24;
    isQ[p] = (off < 8);
    doff[p] = isQ[p] ? (hj * 8 + off) : (hj * 16 + off - 8);
  }

  #pragma unroll
  for (int j = 0; j < 8; ++j) {
    const int atom = a0 + agrp * 8 + j;
    #pragma unroll
    for (int p = 0; p < 3; ++p) {
      float* dst = isQ[p] ? (qarr + (size_t)atom * 128 + doff[p])
                          : (kvarr + (size_t)atom * 256 + doff[p]);
      *dst = acc[j][p];
    }
  }
}

// ---------------------------------------------------------------------------
// CSR build: histogram -> single-block scan -> scatter permutation
// ---------------------------------------------------------------------------
__global__ __launch_bounds__(256) void k_hist(const int* __restrict__ row,
                                              int* __restrict__ cnt) {
  const int e = blockIdx.x * 256 + threadIdx.x;
  if (e < NEDGES) atomicAdd(&cnt[row[e]], 1);
}

__global__ __launch_bounds__(1024) void k_scan(const int* __restrict__ cnt,
                                               int* __restrict__ base,
                                               int* __restrict__ cursor) {
  __shared__ int part[1024];
  const int tid = threadIdx.x;
  const int CH = (NATOMS + 1023) / 1024;  // 49
  const int lo = tid * CH;
  const int hi = (lo + CH < NATOMS) ? (lo + CH) : NATOMS;
  int s = 0;
  for (int i = lo; i < hi; ++i) s += cnt[i];
  part[tid] = s;
  __syncthreads();
  for (int off = 1; off < 1024; off <<= 1) {
    const int v = part[tid];
    const int add = (tid >= off) ? part[tid - off] : 0;
    __syncthreads();
    part[tid] = v + add;
    __syncthreads();
  }
  int run = (tid > 0) ? part[tid - 1] : 0;
  for (int i = lo; i < hi; ++i) {
    base[i] = run;
    cursor[i] = run;
    run += cnt[i];
  }
  if (tid == 0) base[NATOMS] = part[1023];
}

__global__ __launch_bounds__(256) void k_scatter(const int* __restrict__ row,
                                                 int* __restrict__ cursor,
                                                 int* __restrict__ perm) {
  const int e = blockIdx.x * 256 + threadIdx.x;
  if (e < NEDGES) {
    const int p = atomicAdd(&cursor[row[e]], 1);
    perm[p] = e;
  }
}

// ---------------------------------------------------------------------------
// K2: per-atom edge accumulation (no atomics).
// 128 threads per atom (2 atoms per 256-block), thread = channel.
// Loops over the atom's CSR edge list; 4 register accumulators; single
// coalesced write. perm/col prefetched one iteration ahead.
// ---------------------------------------------------------------------------
__global__ __launch_bounds__(256) void k_edge_csr(
    const float* __restrict__ qarr, const float* __restrict__ kvarr,
    const float* __restrict__ ef, const float* __restrict__ evec,
    const float* __restrict__ radial, const int* __restrict__ col,
    const int* __restrict__ base, const int* __restrict__ perm,
    float* __restrict__ mfeat, float* __restrict__ outvec)
{
  const int tid = threadIdx.x;
  const int a = blockIdx.x * 2 + (tid >> 7);
  const int c = tid & 127;
  const int hh = c >> 3;

  const float qv = qarr[(size_t)a * 128 + c];

  float facc = 0.0f, v0 = 0.0f, v1 = 0.0f, v2 = 0.0f;
  const int beg = base[a];
  const int end = base[a + 1];

  int e = 0, cl = 0;
  if (beg < end) { e = perm[beg]; cl = col[e]; }

  for (int i = beg; i < end; ++i) {
    const int e_cur = e, cl_cur = cl;
    if (i + 1 < end) { e = perm[i + 1]; cl = col[e]; }  // prefetch next

    const float* kvrow = kvarr + (size_t)cl_cur * 256 + hh * 16 + (c & 7);
    const float kv = kvrow[0];
    const float vv = kvrow[8];

    float p = qv * kv;
    p += __shfl_xor(p, 1);
    p += __shfl_xor(p, 2);
    p += __shfl_xor(p, 4);
    const float attn =
        0.5f * p * (1.0f + erff(p * 0.70710678118654752f)) * radial[e_cur];

    const float fe = ef[(size_t)e_cur * 128 + c];
    facc = fmaf(vv * fe, attn, facc);

    const float e0 = evec[e_cur * 3 + 0];
    const float e1 = evec[e_cur * 3 + 1];
    const float e2 = evec[e_cur * 3 + 2];
    v0 = fmaf(vv, e0, v0);
    v1 = fmaf(vv, e1, v1);
    v2 = fmaf(vv, e2, v2);
  }

  mfeat[(size_t)a * 128 + c] = facc;
  float* ov = outvec + (size_t)a * 384;
  ov[c] = v0;
  ov[128 + c] = v1;
  ov[256 + c] = v2;
}

// ---------------------------------------------------------------------------
// K3: in-place delta_node_feat = m_feat @ out_w + out_b (m_feat lives in the
// output buffer; each block stages its own 16-atom tile to LDS first).
// ---------------------------------------------------------------------------
__global__ __launch_bounds__(256) void k_out(
    float* __restrict__ io, const float* __restrict__ w,
    const float* __restrict__ bias)
{
  __shared__ float m[16][DIM];
  const int a0 = blockIdx.x * 16;
  const int tid = threadIdx.x;

  #pragma unroll
  for (int i = 0; i < 8; ++i) {
    const int idx = tid + i * 256;
    m[idx >> 7][idx & 127] = io[(size_t)a0 * 128 + idx];
  }
  __syncthreads();

  const int cpart = tid & 127;
  const int agrp = tid >> 7;

  float acc[8];
  const float b0 = bias[cpart];
  #pragma unroll
  for (int j = 0; j < 8; ++j) acc[j] = b0;

  #pragma unroll 4
  for (int k = 0; k < DIM; ++k) {
    const float wk = w[k * 128 + cpart];
    #pragma unroll
    for (int j = 0; j < 8; ++j)
      acc[j] = fmaf(m[agrp * 8 + j][k], wk, acc[j]);
  }

  #pragma unroll
  for (int j = 0; j < 8; ++j)
    io[(size_t)(a0 + agrp * 8 + j) * 128 + cpart] = acc[j];
}

extern "C" void kernel_launch(void* const* d_in, const int* in_sizes, int n_in,
                              void* d_out, int out_size, void* d_ws, size_t ws_size,
                              hipStream_t stream) {
  const float* node_feat = (const float*)d_in[0];
  const float* edge_feat = (const float*)d_in[1];
  const float* edge_vec  = (const float*)d_in[2];
  const float* radial    = (const float*)d_in[3];
  const float* qkv_w     = (const float*)d_in[4];
  const float* qkv_b     = (const float*)d_in[5];
  const float* out_w     = (const float*)d_in[6];
  const float* out_b     = (const float*)d_in[7];
  const float* ln_g      = (const float*)d_in[8];
  const float* ln_b      = (const float*)d_in[9];
  const int*   row       = (const int*)d_in[10];
  const int*   col       = (const int*)d_in[11];

  float* out      = (float*)d_out;
  float* out_feat = out;                           // [50000][128] (m_feat, then GEMM in place)
  float* out_vec  = out + (size_t)NATOMS * DIM;    // [50000][3][128]

  // workspace layout
  float* qarr  = (float*)d_ws;                          // 50000*128
  float* kvarr = qarr + (size_t)NATOMS * 128;           // 50000*256
  int*   cnt    = (int*)(kvarr + (size_t)NATOMS * 256); // 50000
  int*   base   = cnt + NATOMS;                         // 50001
  int*   cursor = base + NATOMS + 1;                    // 50000
  int*   perm   = cursor + NATOMS;                      // 400000

  hipMemsetAsync(cnt, 0, NATOMS * sizeof(int), stream);

  k_ln_qkv<<<NATOMS / 16, 256, 0, stream>>>(node_feat, qkv_w, qkv_b, ln_g, ln_b,
                                            qarr, kvarr);

  const int eb = (NEDGES + 255) / 256;
  k_hist<<<eb, 256, 0, stream>>>(row, cnt);
  k_scan<<<1, 1024, 0, stream>>>(cnt, base, cursor);
  k_scatter<<<eb, 256, 0, stream>>>(row, cursor, perm);

  k_edge_csr<<<NATOMS / 2, 256, 0, stream>>>(qarr, kvarr, edge_feat, edge_vec,
                                             radial, col, base, perm,
                                             out_feat, out_vec);

  k_out<<<NATOMS / 16, 256, 0, stream>>>(out_feat, out_w, out_b);
}

// Round 3
// 394.914 us; speedup vs baseline: 2.0646x; 1.2573x over previous
//
#include <hip/hip_runtime.h>
#include <math.h>

#define DIM 128
#define NHEADS 16
#define DPH 8
#define NATOMS 50000
#define NEDGES 400000
#define LN_EPS 1e-5f

typedef float f32x4 __attribute__((ext_vector_type(4)));
typedef short s16x8 __attribute__((ext_vector_type(8)));

static __device__ __forceinline__ unsigned short f2bf(float f) {
  unsigned u = __builtin_bit_cast(unsigned, f);
  unsigned r = (u + 0x7FFFu + ((u >> 16) & 1u)) >> 16;  // RNE
  return (unsigned short)r;
}

// fast GELU (tanh form): x * sigmoid(2*c0*(x + c1*x^3))
static __device__ __forceinline__ float gelu_fast(float x) {
  const float c0 = 0.7978845608028654f;
  const float c1 = 0.044715f;
  float u = c0 * (x + c1 * x * x * x);
  return __fdividef(x, 1.0f + __expf(-2.0f * u));
}

// ---------------------------------------------------------------------------
// Weight convert/transpose: qkv_w [128][384] -> wTq bf16 [384][128];
// out_w [128][128] -> wTo bf16 [128][128] (col-major: wT[c][k]).
// ---------------------------------------------------------------------------
__global__ __launch_bounds__(256) void k_convert_w(
    const float* __restrict__ qkv_w, const float* __restrict__ out_w,
    unsigned short* __restrict__ wTq, unsigned short* __restrict__ wTo)
{
  const int idx = blockIdx.x * 256 + threadIdx.x;
  if (idx < 384 * 128) {
    const int c = idx >> 7, k = idx & 127;
    wTq[idx] = f2bf(qkv_w[k * 384 + c]);
  } else {
    const int i2 = idx - 384 * 128;
    const int c = i2 >> 7, k = i2 & 127;
    wTo[i2] = f2bf(out_w[k * 128 + c]);
  }
}

// ---------------------------------------------------------------------------
// K1: fused LayerNorm + QKV projection (MFMA).
// Block = 256 (4 waves) handles 16 atoms. Phase 1: LN into padded LDS f32.
// Phase 2: wave w computes cols [w*96, w*96+96) via 16x16x32 bf16 MFMA.
// Epilogue scatters q into qarr[atom][128] and k,v interleaved as float2
// into kvarr[atom][head*8+elem] = {k, v}.
// ---------------------------------------------------------------------------
__global__ __launch_bounds__(256) void k_ln_qkv(
    const float* __restrict__ node, const unsigned short* __restrict__ wTq,
    const float* __restrict__ bias, const float* __restrict__ g,
    const float* __restrict__ beta, float* __restrict__ qarr,
    float* __restrict__ kvarr)
{
  __shared__ float hpad[16][132];
  const int a0 = blockIdx.x * 16;
  const int tid = threadIdx.x;
  const int wid = tid >> 6;
  const int lane = tid & 63;

  // phase 1: LayerNorm (wave `wid` does atoms wid*4 .. +3)
  for (int j = 0; j < 4; ++j) {
    const int a = wid * 4 + j;
    const float x0 = node[(size_t)(a0 + a) * DIM + lane];
    const float x1 = node[(size_t)(a0 + a) * DIM + 64 + lane];
    float s = x0 + x1;
    #pragma unroll
    for (int m = 1; m < 64; m <<= 1) s += __shfl_xor(s, m);
    const float mu = s * (1.0f / 128.0f);
    const float d0 = x0 - mu, d1 = x1 - mu;
    float v = d0 * d0 + d1 * d1;
    #pragma unroll
    for (int m = 1; m < 64; m <<= 1) v += __shfl_xor(v, m);
    const float rs = rsqrtf(v * (1.0f / 128.0f) + LN_EPS);
    hpad[a][lane]      = d0 * rs * g[lane]      + beta[lane];
    hpad[a][64 + lane] = d1 * rs * g[64 + lane] + beta[64 + lane];
  }
  __syncthreads();

  // phase 2: MFMA
  const int lrow = lane & 15;   // A row / B col / D col
  const int lquad = lane >> 4;  // 0..3
  const int colbase = wid * 96;

  // A-frags: h[lrow][ks*32 + lquad*8 .. +7] -> bf16x8
  s16x8 afrag[4];
  #pragma unroll
  for (int ks = 0; ks < 4; ++ks) {
    const int koff = ks * 32 + lquad * 8;
    const float4 p0 = *reinterpret_cast<const float4*>(&hpad[lrow][koff]);
    const float4 p1 = *reinterpret_cast<const float4*>(&hpad[lrow][koff + 4]);
    s16x8 af;
    af[0] = (short)f2bf(p0.x); af[1] = (short)f2bf(p0.y);
    af[2] = (short)f2bf(p0.z); af[3] = (short)f2bf(p0.w);
    af[4] = (short)f2bf(p1.x); af[5] = (short)f2bf(p1.y);
    af[6] = (short)f2bf(p1.z); af[7] = (short)f2bf(p1.w);
    afrag[ks] = af;
  }

  f32x4 acc[6];
  #pragma unroll
  for (int t = 0; t < 6; ++t) acc[t] = (f32x4){0.f, 0.f, 0.f, 0.f};

  #pragma unroll
  for (int t = 0; t < 6; ++t) {
    const int cg = colbase + t * 16 + lrow;  // B col for this lane
    #pragma unroll
    for (int ks = 0; ks < 4; ++ks) {
      const s16x8 bf = *reinterpret_cast<const s16x8*>(
          &wTq[(size_t)cg * 128 + ks * 32 + lquad * 8]);
      acc[t] = __builtin_amdgcn_mfma_f32_16x16x32_bf16(afrag[ks], bf, acc[t], 0, 0, 0);
    }
  }

  // epilogue: D col = lane&15, row = lquad*4 + r
  #pragma unroll
  for (int t = 0; t < 6; ++t) {
    const int cg = colbase + t * 16 + lrow;
    const float bz = bias[cg];
    const int hj = cg / 24;
    const int off = cg - hj * 24;
    #pragma unroll
    for (int r = 0; r < 4; ++r) {
      const int atom = a0 + lquad * 4 + r;
      const float val = acc[t][r] + bz;
      if (off < 8) {
        qarr[(size_t)atom * 128 + hj * 8 + off] = val;
      } else if (off < 16) {
        kvarr[(size_t)atom * 256 + (hj * 8 + off - 8) * 2] = val;      // k
      } else {
        kvarr[(size_t)atom * 256 + (hj * 8 + off - 16) * 2 + 1] = val; // v
      }
    }
  }
}

// ---------------------------------------------------------------------------
// CSR build: histogram -> single-block scan -> scatter permutation
// ---------------------------------------------------------------------------
__global__ __launch_bounds__(256) void k_hist(const int* __restrict__ row,
                                              int* __restrict__ cnt) {
  const int e = blockIdx.x * 256 + threadIdx.x;
  if (e < NEDGES) atomicAdd(&cnt[row[e]], 1);
}

__global__ __launch_bounds__(1024) void k_scan(const int* __restrict__ cnt,
                                               int* __restrict__ base,
                                               int* __restrict__ cursor) {
  __shared__ int part[1024];
  const int tid = threadIdx.x;
  const int CH = (NATOMS + 1023) / 1024;  // 49
  const int lo = tid * CH;
  const int hi = (lo + CH < NATOMS) ? (lo + CH) : NATOMS;
  int s = 0;
  for (int i = lo; i < hi; ++i) s += cnt[i];
  part[tid] = s;
  __syncthreads();
  for (int off = 1; off < 1024; off <<= 1) {
    const int v = part[tid];
    const int add = (tid >= off) ? part[tid - off] : 0;
    __syncthreads();
    part[tid] = v + add;
    __syncthreads();
  }
  int run = (tid > 0) ? part[tid - 1] : 0;
  for (int i = lo; i < hi; ++i) {
    base[i] = run;
    cursor[i] = run;
    run += cnt[i];
  }
  if (tid == 0) base[NATOMS] = part[1023];
}

__global__ __launch_bounds__(256) void k_scatter(const int* __restrict__ row,
                                                 int* __restrict__ cursor,
                                                 int* __restrict__ perm) {
  const int e = blockIdx.x * 256 + threadIdx.x;
  if (e < NEDGES) {
    const int p = atomicAdd(&cursor[row[e]], 1);
    perm[p] = e;
  }
}

// ---------------------------------------------------------------------------
// K2: per-atom edge accumulation, unroll-2 with index prefetch.
// 128 threads per atom (2 atoms / block). kv interleaved float2 {k,v}.
// Writes m_feat as bf16 (feeds MFMA k_out) and m_vec f32 direct to output.
// ---------------------------------------------------------------------------
__global__ __launch_bounds__(256) void k_edge_csr(
    const float* __restrict__ qarr, const float2* __restrict__ kv,
    const float* __restrict__ ef, const float* __restrict__ evec,
    const float* __restrict__ radial, const int* __restrict__ col,
    const int* __restrict__ base, const int* __restrict__ perm,
    unsigned short* __restrict__ mfeatb, float* __restrict__ outvec)
{
  const int tid = threadIdx.x;
  const int a = blockIdx.x * 2 + (tid >> 7);
  const int c = tid & 127;
  const int chan = (c >> 3) * 8 + (c & 7);  // == c, but keep mapping explicit

  const float qv = qarr[(size_t)a * 128 + c];

  float facc = 0.0f, v0 = 0.0f, v1 = 0.0f, v2 = 0.0f;
  const int beg = base[a];
  const int end = base[a + 1];

  int eA = 0, eB = 0, clA = 0, clB = 0;
  if (beg < end)     { eA = perm[beg];     clA = col[eA]; }
  if (beg + 1 < end) { eB = perm[beg + 1]; clB = col[eB]; }

  for (int i = beg; i < end; i += 2) {
    const int e0 = eA, c0 = clA, e1 = eB, c1 = clB;
    const bool has1 = (i + 1 < end);
    if (i + 2 < end) { eA = perm[i + 2]; clA = col[eA]; }
    if (i + 3 < end) { eB = perm[i + 3]; clB = col[eB]; }

    // edge 0 loads
    const float2 kv0 = kv[(size_t)c0 * 128 + chan];
    const float r0 = radial[e0];
    const float fe0 = ef[(size_t)e0 * 128 + c];
    const float e00 = evec[e0 * 3 + 0];
    const float e01 = evec[e0 * 3 + 1];
    const float e02 = evec[e0 * 3 + 2];

    // edge 1 loads (guarded; zeros make its contribution exactly 0)
    float2 kv1 = make_float2(0.f, 0.f);
    float r1 = 0.f, fe1 = 0.f, e10 = 0.f, e11 = 0.f, e12 = 0.f;
    if (has1) {
      kv1 = kv[(size_t)c1 * 128 + chan];
      r1 = radial[e1];
      fe1 = ef[(size_t)e1 * 128 + c];
      e10 = evec[e1 * 3 + 0];
      e11 = evec[e1 * 3 + 1];
      e12 = evec[e1 * 3 + 2];
    }

    float p0 = qv * kv0.x;
    p0 += __shfl_xor(p0, 1); p0 += __shfl_xor(p0, 2); p0 += __shfl_xor(p0, 4);
    float p1 = qv * kv1.x;
    p1 += __shfl_xor(p1, 1); p1 += __shfl_xor(p1, 2); p1 += __shfl_xor(p1, 4);

    const float at0 = gelu_fast(p0) * r0;
    const float at1 = gelu_fast(p1) * r1;

    facc = fmaf(kv0.y * fe0, at0, facc);
    facc = fmaf(kv1.y * fe1, at1, facc);
    v0 = fmaf(kv0.y, e00, fmaf(kv1.y, e10, v0));
    v1 = fmaf(kv0.y, e01, fmaf(kv1.y, e11, v1));
    v2 = fmaf(kv0.y, e02, fmaf(kv1.y, e12, v2));
  }

  mfeatb[(size_t)a * 128 + c] = f2bf(facc);
  float* ov = outvec + (size_t)a * 384;
  ov[c] = v0;
  ov[128 + c] = v1;
  ov[256 + c] = v2;
}

// ---------------------------------------------------------------------------
// K3: delta_node_feat = m_feat(bf16) @ out_wT(bf16) + out_b via MFMA.
// Block = 256 (4 waves), 16 atoms; wave w covers cols [w*32, w*32+32).
// ---------------------------------------------------------------------------
__global__ __launch_bounds__(256) void k_out(
    const unsigned short* __restrict__ mfeatb,
    const unsigned short* __restrict__ wTo,
    const float* __restrict__ bias, float* __restrict__ out)
{
  const int a0 = blockIdx.x * 16;
  const int tid = threadIdx.x;
  const int wid = tid >> 6;
  const int lane = tid & 63;
  const int lrow = lane & 15;
  const int lquad = lane >> 4;

  s16x8 afrag[4];
  #pragma unroll
  for (int ks = 0; ks < 4; ++ks)
    afrag[ks] = *reinterpret_cast<const s16x8*>(
        &mfeatb[(size_t)(a0 + lrow) * 128 + ks * 32 + lquad * 8]);

  f32x4 acc[2];
  acc[0] = (f32x4){0.f, 0.f, 0.f, 0.f};
  acc[1] = (f32x4){0.f, 0.f, 0.f, 0.f};

  #pragma unroll
  for (int t = 0; t < 2; ++t) {
    const int cg = wid * 32 + t * 16 + lrow;
    #pragma unroll
    for (int ks = 0; ks < 4; ++ks) {
      const s16x8 bf = *reinterpret_cast<const s16x8*>(
          &wTo[(size_t)cg * 128 + ks * 32 + lquad * 8]);
      acc[t] = __builtin_amdgcn_mfma_f32_16x16x32_bf16(afrag[ks], bf, acc[t], 0, 0, 0);
    }
  }

  #pragma unroll
  for (int t = 0; t < 2; ++t) {
    const int cg = wid * 32 + t * 16 + lrow;
    const float bz = bias[cg];
    #pragma unroll
    for (int r = 0; r < 4; ++r) {
      const int atom = a0 + lquad * 4 + r;
      out[(size_t)atom * 128 + cg] = acc[t][r] + bz;
    }
  }
}

extern "C" void kernel_launch(void* const* d_in, const int* in_sizes, int n_in,
                              void* d_out, int out_size, void* d_ws, size_t ws_size,
                              hipStream_t stream) {
  const float* node_feat = (const float*)d_in[0];
  const float* edge_feat = (const float*)d_in[1];
  const float* edge_vec  = (const float*)d_in[2];
  const float* radial    = (const float*)d_in[3];
  const float* qkv_w     = (const float*)d_in[4];
  const float* qkv_b     = (const float*)d_in[5];
  const float* out_w     = (const float*)d_in[6];
  const float* out_b     = (const float*)d_in[7];
  const float* ln_g      = (const float*)d_in[8];
  const float* ln_b      = (const float*)d_in[9];
  const int*   row       = (const int*)d_in[10];
  const int*   col       = (const int*)d_in[11];

  float* out      = (float*)d_out;
  float* out_feat = out;                           // [50000][128]
  float* out_vec  = out + (size_t)NATOMS * DIM;    // [50000][3][128]

  // workspace layout (16B-aligned sections)
  float* qarr   = (float*)d_ws;                                 // 50000*128 f32
  float* kvarr  = qarr + (size_t)NATOMS * 128;                  // 50000*256 f32 (float2 interleaved)
  unsigned short* mfeatb = (unsigned short*)(kvarr + (size_t)NATOMS * 256); // 50000*128 bf16
  unsigned short* wTq = mfeatb + (size_t)NATOMS * 128;          // 384*128 bf16
  unsigned short* wTo = wTq + 384 * 128;                        // 128*128 bf16
  int* cnt    = (int*)(wTo + 128 * 128);                        // 50000
  int* base   = cnt + NATOMS;                                   // 50001
  int* cursor = base + NATOMS + 1;                              // 50000
  int* perm   = cursor + NATOMS;                                // 400000

  hipMemsetAsync(cnt, 0, NATOMS * sizeof(int), stream);

  k_convert_w<<<(384 * 128 + 128 * 128) / 256, 256, 0, stream>>>(qkv_w, out_w, wTq, wTo);

  const int eb = (NEDGES + 255) / 256;
  k_hist<<<eb, 256, 0, stream>>>(row, cnt);
  k_scan<<<1, 1024, 0, stream>>>(cnt, base, cursor);
  k_scatter<<<eb, 256, 0, stream>>>(row, cursor, perm);

  k_ln_qkv<<<NATOMS / 16, 256, 0, stream>>>(node_feat, wTq, qkv_b, ln_g, ln_b,
                                            qarr, kvarr);

  k_edge_csr<<<NATOMS / 2, 256, 0, stream>>>(qarr, (const float2*)kvarr,
                                             edge_feat, edge_vec, radial, col,
                                             base, perm, mfeatb, out_vec);

  k_out<<<NATOMS / 16, 256, 0, stream>>>(mfeatb, wTo, out_b, out_feat);
}

// Round 4
// 361.087 us; speedup vs baseline: 2.2580x; 1.0937x over previous
//
#include <hip/hip_runtime.h>
#include <math.h>

#define DIM 128
#define NHEADS 16
#define DPH 8
#define NATOMS 50000
#define NEDGES 400000
#define LN_EPS 1e-5f

typedef float f32x4 __attribute__((ext_vector_type(4)));
typedef short s16x8 __attribute__((ext_vector_type(8)));

static __device__ __forceinline__ unsigned short f2bf(float f) {
  unsigned u = __builtin_bit_cast(unsigned, f);
  unsigned r = (u + 0x7FFFu + ((u >> 16) & 1u)) >> 16;  // RNE
  return (unsigned short)r;
}

// fast GELU (tanh form): x * sigmoid(2*c0*(x + c1*x^3))
static __device__ __forceinline__ float gelu_fast(float x) {
  const float c0 = 0.7978845608028654f;
  const float c1 = 0.044715f;
  float u = c0 * (x + c1 * x * x * x);
  return __fdividef(x, 1.0f + __expf(-2.0f * u));
}

// ---------------------------------------------------------------------------
// Weight convert/transpose: qkv_w [128][384] -> wTq bf16 [384][128];
// out_w [128][128] -> wTo bf16 [128][128] (col-major: wT[c][k]).
// ---------------------------------------------------------------------------
__global__ __launch_bounds__(256) void k_convert_w(
    const float* __restrict__ qkv_w, const float* __restrict__ out_w,
    unsigned short* __restrict__ wTq, unsigned short* __restrict__ wTo)
{
  const int idx = blockIdx.x * 256 + threadIdx.x;
  if (idx < 384 * 128) {
    const int c = idx >> 7, k = idx & 127;
    wTq[idx] = f2bf(qkv_w[k * 384 + c]);
  } else {
    const int i2 = idx - 384 * 128;
    const int c = i2 >> 7, k = i2 & 127;
    wTo[i2] = f2bf(out_w[k * 128 + c]);
  }
}

// ---------------------------------------------------------------------------
// K1: fused LayerNorm + QKV projection (MFMA), LDS-staged coalesced epilogue.
// Block = 256 (4 waves) handles 16 atoms. Wave w -> cols [w*96, w*96+96).
// so[atom][0..127] = q channels, so[atom][128..383] = interleaved {k,v}.
// ---------------------------------------------------------------------------
__global__ __launch_bounds__(256) void k_ln_qkv(
    const float* __restrict__ node, const unsigned short* __restrict__ wTq,
    const float* __restrict__ bias, const float* __restrict__ g,
    const float* __restrict__ beta, float* __restrict__ qarr,
    float* __restrict__ kvarr)
{
  __shared__ float hpad[16][132];
  __shared__ float so[16][388];
  const int a0 = blockIdx.x * 16;
  const int tid = threadIdx.x;
  const int wid = tid >> 6;
  const int lane = tid & 63;

  // phase 1: LayerNorm (wave `wid` does atoms wid*4 .. +3)
  for (int j = 0; j < 4; ++j) {
    const int a = wid * 4 + j;
    const float x0 = node[(size_t)(a0 + a) * DIM + lane];
    const float x1 = node[(size_t)(a0 + a) * DIM + 64 + lane];
    float s = x0 + x1;
    #pragma unroll
    for (int m = 1; m < 64; m <<= 1) s += __shfl_xor(s, m);
    const float mu = s * (1.0f / 128.0f);
    const float d0 = x0 - mu, d1 = x1 - mu;
    float v = d0 * d0 + d1 * d1;
    #pragma unroll
    for (int m = 1; m < 64; m <<= 1) v += __shfl_xor(v, m);
    const float rs = rsqrtf(v * (1.0f / 128.0f) + LN_EPS);
    hpad[a][lane]      = d0 * rs * g[lane]      + beta[lane];
    hpad[a][64 + lane] = d1 * rs * g[64 + lane] + beta[64 + lane];
  }
  __syncthreads();

  // phase 2: MFMA
  const int lrow = lane & 15;
  const int lquad = lane >> 4;
  const int colbase = wid * 96;

  s16x8 afrag[4];
  #pragma unroll
  for (int ks = 0; ks < 4; ++ks) {
    const int koff = ks * 32 + lquad * 8;
    const float4 p0 = *reinterpret_cast<const float4*>(&hpad[lrow][koff]);
    const float4 p1 = *reinterpret_cast<const float4*>(&hpad[lrow][koff + 4]);
    s16x8 af;
    af[0] = (short)f2bf(p0.x); af[1] = (short)f2bf(p0.y);
    af[2] = (short)f2bf(p0.z); af[3] = (short)f2bf(p0.w);
    af[4] = (short)f2bf(p1.x); af[5] = (short)f2bf(p1.y);
    af[6] = (short)f2bf(p1.z); af[7] = (short)f2bf(p1.w);
    afrag[ks] = af;
  }

  f32x4 acc[6];
  #pragma unroll
  for (int t = 0; t < 6; ++t) acc[t] = (f32x4){0.f, 0.f, 0.f, 0.f};

  #pragma unroll
  for (int t = 0; t < 6; ++t) {
    const int cg = colbase + t * 16 + lrow;
    #pragma unroll
    for (int ks = 0; ks < 4; ++ks) {
      const s16x8 bf = *reinterpret_cast<const s16x8*>(
          &wTq[(size_t)cg * 128 + ks * 32 + lquad * 8]);
      acc[t] = __builtin_amdgcn_mfma_f32_16x16x32_bf16(afrag[ks], bf, acc[t], 0, 0, 0);
    }
  }

  // epilogue: stage into LDS in the q/kv split layout
  #pragma unroll
  for (int t = 0; t < 6; ++t) {
    const int cg = colbase + t * 16 + lrow;
    const float bz = bias[cg];
    const int hj = cg / 24;
    const int off = cg - hj * 24;
    int moff;
    if (off < 8)       moff = hj * 8 + off;                 // q
    else if (off < 16) moff = 128 + (hj * 8 + off - 8) * 2; // k
    else               moff = 128 + (hj * 8 + off - 16) * 2 + 1; // v
    #pragma unroll
    for (int r = 0; r < 4; ++r)
      so[lquad * 4 + r][moff] = acc[t][r] + bz;
  }
  __syncthreads();

  // coalesced float4 stores: 96 float4 per atom row (32 q + 64 kv)
  f32x4* q4  = (f32x4*)qarr;
  f32x4* kv4 = (f32x4*)kvarr;
  #pragma unroll
  for (int kk = 0; kk < 6; ++kk) {
    const int idx4 = tid + kk * 256;     // 0..1535
    const int rowi = idx4 / 96;
    const int c4 = idx4 - rowi * 96;
    const f32x4 val = *reinterpret_cast<const f32x4*>(&so[rowi][c4 * 4]);
    if (c4 < 32) q4[(size_t)(a0 + rowi) * 32 + c4] = val;
    else         kv4[(size_t)(a0 + rowi) * 64 + (c4 - 32)] = val;
  }
}

// ---------------------------------------------------------------------------
// CSR build: histogram -> single-block scan -> scatter permutation
// ---------------------------------------------------------------------------
__global__ __launch_bounds__(256) void k_hist(const int* __restrict__ row,
                                              int* __restrict__ cnt) {
  const int e = blockIdx.x * 256 + threadIdx.x;
  if (e < NEDGES) atomicAdd(&cnt[row[e]], 1);
}

__global__ __launch_bounds__(1024) void k_scan(const int* __restrict__ cnt,
                                               int* __restrict__ base,
                                               int* __restrict__ cursor) {
  __shared__ int part[1024];
  const int tid = threadIdx.x;
  const int CH = (NATOMS + 1023) / 1024;  // 49
  const int lo = tid * CH;
  const int hi = (lo + CH < NATOMS) ? (lo + CH) : NATOMS;
  int s = 0;
  for (int i = lo; i < hi; ++i) s += cnt[i];
  part[tid] = s;
  __syncthreads();
  for (int off = 1; off < 1024; off <<= 1) {
    const int v = part[tid];
    const int add = (tid >= off) ? part[tid - off] : 0;
    __syncthreads();
    part[tid] = v + add;
    __syncthreads();
  }
  int run = (tid > 0) ? part[tid - 1] : 0;
  for (int i = lo; i < hi; ++i) {
    base[i] = run;
    cursor[i] = run;
    run += cnt[i];
  }
  if (tid == 0) base[NATOMS] = part[1023];
}

__global__ __launch_bounds__(256) void k_scatter(const int* __restrict__ row,
                                                 int* __restrict__ cursor,
                                                 int* __restrict__ perm) {
  const int e = blockIdx.x * 256 + threadIdx.x;
  if (e < NEDGES) {
    const int p = atomicAdd(&cursor[row[e]], 1);
    perm[p] = e;
  }
}

// ---------------------------------------------------------------------------
// K2: per-atom edge accumulation, software-pipelined.
// 128 threads per atom (2 atoms / block). Data for pair n+1 issued before
// computing pair n; indices (perm->col, scalar path) run two pairs ahead.
// Invalid second edges are masked by zeroing kv.
// ---------------------------------------------------------------------------
__global__ __launch_bounds__(256) void k_edge_csr(
    const float* __restrict__ qarr, const float2* __restrict__ kv,
    const float* __restrict__ ef, const float* __restrict__ evec,
    const float* __restrict__ radial, const int* __restrict__ col,
    const int* __restrict__ base, const int* __restrict__ perm,
    unsigned short* __restrict__ mfeatb, float* __restrict__ outvec)
{
  const int tid = threadIdx.x;
  const int a = blockIdx.x * 2 + (tid >> 7);
  const int c = tid & 127;

  const int beg = base[a];
  const int end = base[a + 1];

  float facc = 0.f, v0 = 0.f, v1 = 0.f, v2 = 0.f;

  if (beg < end) {
    const float qv = qarr[(size_t)a * 128 + c];
    const int last = end - 1;

    int nE0, nC0, nE1, nC1;
    float2 kv0, kv1;
    float r0, r1, fe0, fe1;
    float a00, a01, a02, b00, b01, b02;

    // idx pair 0
    {
      const int i1 = (beg + 1 <= last) ? beg + 1 : last;
      nE0 = __builtin_amdgcn_readfirstlane(perm[beg]);
      nE1 = __builtin_amdgcn_readfirstlane(perm[i1]);
      nC0 = __builtin_amdgcn_readfirstlane(col[nE0]);
      nC1 = __builtin_amdgcn_readfirstlane(col[nE1]);
    }
    // data pair 0
    kv0 = kv[(size_t)nC0 * 128 + c];
    kv1 = kv[(size_t)nC1 * 128 + c];
    fe0 = ef[(size_t)nE0 * 128 + c];
    fe1 = ef[(size_t)nE1 * 128 + c];
    r0 = radial[nE0]; r1 = radial[nE1];
    a00 = evec[(size_t)nE0 * 3]; a01 = evec[(size_t)nE0 * 3 + 1]; a02 = evec[(size_t)nE0 * 3 + 2];
    b00 = evec[(size_t)nE1 * 3]; b01 = evec[(size_t)nE1 * 3 + 1]; b02 = evec[(size_t)nE1 * 3 + 2];
    // idx pair 1
    {
      const int j0 = (beg + 2 <= last) ? beg + 2 : last;
      const int j1 = (beg + 3 <= last) ? beg + 3 : last;
      nE0 = __builtin_amdgcn_readfirstlane(perm[j0]);
      nE1 = __builtin_amdgcn_readfirstlane(perm[j1]);
      nC0 = __builtin_amdgcn_readfirstlane(col[nE0]);
      nC1 = __builtin_amdgcn_readfirstlane(col[nE1]);
    }

    for (int i = beg; i < end; i += 2) {
      // stage current pair into use-regs
      float2 ukv0 = kv0, ukv1 = kv1;
      const float ur0 = r0, ur1 = r1, uf0 = fe0, uf1 = fe1;
      const float ua0 = a00, ua1 = a01, ua2 = a02;
      const float ub0 = b00, ub1 = b01, ub2 = b02;

      // issue next pair's data loads + idx loads two pairs ahead
      if (i + 2 < end) {
        kv0 = kv[(size_t)nC0 * 128 + c];
        kv1 = kv[(size_t)nC1 * 128 + c];
        fe0 = ef[(size_t)nE0 * 128 + c];
        fe1 = ef[(size_t)nE1 * 128 + c];
        r0 = radial[nE0]; r1 = radial[nE1];
        a00 = evec[(size_t)nE0 * 3]; a01 = evec[(size_t)nE0 * 3 + 1]; a02 = evec[(size_t)nE0 * 3 + 2];
        b00 = evec[(size_t)nE1 * 3]; b01 = evec[(size_t)nE1 * 3 + 1]; b02 = evec[(size_t)nE1 * 3 + 2];
        const int j0 = (i + 4 <= last) ? i + 4 : last;
        const int j1 = (i + 5 <= last) ? i + 5 : last;
        nE0 = __builtin_amdgcn_readfirstlane(perm[j0]);
        nE1 = __builtin_amdgcn_readfirstlane(perm[j1]);
        nC0 = __builtin_amdgcn_readfirstlane(col[nE0]);
        nC1 = __builtin_amdgcn_readfirstlane(col[nE1]);
      }

      // mask invalid second edge (zeros kill both the dot and the products;
      // gelu(0)=0 keeps everything finite)
      const float m1 = (i + 1 < end) ? 1.f : 0.f;
      ukv1.x *= m1; ukv1.y *= m1;

      float p0 = qv * ukv0.x;
      p0 += __shfl_xor(p0, 1); p0 += __shfl_xor(p0, 2); p0 += __shfl_xor(p0, 4);
      float p1 = qv * ukv1.x;
      p1 += __shfl_xor(p1, 1); p1 += __shfl_xor(p1, 2); p1 += __shfl_xor(p1, 4);

      const float at0 = gelu_fast(p0) * ur0;
      const float at1 = gelu_fast(p1) * ur1;

      facc = fmaf(ukv0.y * uf0, at0, facc);
      facc = fmaf(ukv1.y * uf1, at1, facc);
      v0 = fmaf(ukv0.y, ua0, fmaf(ukv1.y, ub0, v0));
      v1 = fmaf(ukv0.y, ua1, fmaf(ukv1.y, ub1, v1));
      v2 = fmaf(ukv0.y, ua2, fmaf(ukv1.y, ub2, v2));
    }
  }

  mfeatb[(size_t)a * 128 + c] = f2bf(facc);
  float* ov = outvec + (size_t)a * 384;
  ov[c] = v0;
  ov[128 + c] = v1;
  ov[256 + c] = v2;
}

// ---------------------------------------------------------------------------
// K3: delta_node_feat = m_feat(bf16) @ out_wT(bf16) + out_b via MFMA,
// LDS-staged coalesced epilogue.
// ---------------------------------------------------------------------------
__global__ __launch_bounds__(256) void k_out(
    const unsigned short* __restrict__ mfeatb,
    const unsigned short* __restrict__ wTo,
    const float* __restrict__ bias, float* __restrict__ out)
{
  __shared__ float so[16][132];
  const int a0 = blockIdx.x * 16;
  const int tid = threadIdx.x;
  const int wid = tid >> 6;
  const int lane = tid & 63;
  const int lrow = lane & 15;
  const int lquad = lane >> 4;

  s16x8 afrag[4];
  #pragma unroll
  for (int ks = 0; ks < 4; ++ks)
    afrag[ks] = *reinterpret_cast<const s16x8*>(
        &mfeatb[(size_t)(a0 + lrow) * 128 + ks * 32 + lquad * 8]);

  f32x4 acc[2];
  acc[0] = (f32x4){0.f, 0.f, 0.f, 0.f};
  acc[1] = (f32x4){0.f, 0.f, 0.f, 0.f};

  #pragma unroll
  for (int t = 0; t < 2; ++t) {
    const int cg = wid * 32 + t * 16 + lrow;
    #pragma unroll
    for (int ks = 0; ks < 4; ++ks) {
      const s16x8 bf = *reinterpret_cast<const s16x8*>(
          &wTo[(size_t)cg * 128 + ks * 32 + lquad * 8]);
      acc[t] = __builtin_amdgcn_mfma_f32_16x16x32_bf16(afrag[ks], bf, acc[t], 0, 0, 0);
    }
  }

  #pragma unroll
  for (int t = 0; t < 2; ++t) {
    const int cg = wid * 32 + t * 16 + lrow;
    const float bz = bias[cg];
    #pragma unroll
    for (int r = 0; r < 4; ++r)
      so[lquad * 4 + r][cg] = acc[t][r] + bz;
  }
  __syncthreads();

  f32x4* out4 = (f32x4*)out;
  #pragma unroll
  for (int kk = 0; kk < 2; ++kk) {
    const int idx4 = tid + kk * 256;   // 0..511
    const int rowi = idx4 >> 5;
    const int c4 = idx4 & 31;
    out4[(size_t)(a0 + rowi) * 32 + c4] =
        *reinterpret_cast<const f32x4*>(&so[rowi][c4 * 4]);
  }
}

extern "C" void kernel_launch(void* const* d_in, const int* in_sizes, int n_in,
                              void* d_out, int out_size, void* d_ws, size_t ws_size,
                              hipStream_t stream) {
  const float* node_feat = (const float*)d_in[0];
  const float* edge_feat = (const float*)d_in[1];
  const float* edge_vec  = (const float*)d_in[2];
  const float* radial    = (const float*)d_in[3];
  const float* qkv_w     = (const float*)d_in[4];
  const float* qkv_b     = (const float*)d_in[5];
  const float* out_w     = (const float*)d_in[6];
  const float* out_b     = (const float*)d_in[7];
  const float* ln_g      = (const float*)d_in[8];
  const float* ln_b      = (const float*)d_in[9];
  const int*   row       = (const int*)d_in[10];
  const int*   col       = (const int*)d_in[11];

  float* out      = (float*)d_out;
  float* out_feat = out;                           // [50000][128]
  float* out_vec  = out + (size_t)NATOMS * DIM;    // [50000][3][128]

  // workspace layout (16B-aligned sections)
  float* qarr   = (float*)d_ws;                                 // 50000*128 f32
  float* kvarr  = qarr + (size_t)NATOMS * 128;                  // 50000*256 f32 (float2 interleaved)
  unsigned short* mfeatb = (unsigned short*)(kvarr + (size_t)NATOMS * 256); // 50000*128 bf16
  unsigned short* wTq = mfeatb + (size_t)NATOMS * 128;          // 384*128 bf16
  unsigned short* wTo = wTq + 384 * 128;                        // 128*128 bf16
  int* cnt    = (int*)(wTo + 128 * 128);                        // 50000
  int* base   = cnt + NATOMS;                                   // 50001
  int* cursor = base + NATOMS + 1;                              // 50000
  int* perm   = cursor + NATOMS;                                // 400000

  hipMemsetAsync(cnt, 0, NATOMS * sizeof(int), stream);

  k_convert_w<<<(384 * 128 + 128 * 128) / 256, 256, 0, stream>>>(qkv_w, out_w, wTq, wTo);

  const int eb = (NEDGES + 255) / 256;
  k_hist<<<eb, 256, 0, stream>>>(row, cnt);
  k_scan<<<1, 1024, 0, stream>>>(cnt, base, cursor);
  k_scatter<<<eb, 256, 0, stream>>>(row, cursor, perm);

  k_ln_qkv<<<NATOMS / 16, 256, 0, stream>>>(node_feat, wTq, qkv_b, ln_g, ln_b,
                                            qarr, kvarr);

  k_edge_csr<<<NATOMS / 2, 256, 0, stream>>>(qarr, (const float2*)kvarr,
                                             edge_feat, edge_vec, radial, col,
                                             base, perm, mfeatb, out_vec);

  k_out<<<NATOMS / 16, 256, 0, stream>>>(mfeatb, wTo, out_b, out_feat);
}

// Round 5
// 249.680 us; speedup vs baseline: 3.2655x; 1.4462x over previous
//
#include <hip/hip_runtime.h>
#include <math.h>

#define DIM 128
#define NHEADS 16
#define DPH 8
#define NATOMS 50000
#define NEDGES 400000
#define LN_EPS 1e-5f

typedef float f32x4 __attribute__((ext_vector_type(4)));
typedef short s16x8 __attribute__((ext_vector_type(8)));

static __device__ __forceinline__ unsigned short f2bf(float f) {
  unsigned u = __builtin_bit_cast(unsigned, f);
  unsigned r = (u + 0x7FFFu + ((u >> 16) & 1u)) >> 16;  // RNE
  return (unsigned short)r;
}

// fast GELU (tanh form): x * sigmoid(2*c0*(x + c1*x^3))
static __device__ __forceinline__ float gelu_fast(float x) {
  const float c0 = 0.7978845608028654f;
  const float c1 = 0.044715f;
  float u = c0 * (x + c1 * x * x * x);
  return __fdividef(x, 1.0f + __expf(-2.0f * u));
}

// ---------------------------------------------------------------------------
// Weight convert/transpose: qkv_w [128][384] -> wTq bf16 [384][128];
// out_w [128][128] -> wTo bf16 [128][128] (col-major: wT[c][k]).
// ---------------------------------------------------------------------------
__global__ __launch_bounds__(256) void k_convert_w(
    const float* __restrict__ qkv_w, const float* __restrict__ out_w,
    unsigned short* __restrict__ wTq, unsigned short* __restrict__ wTo)
{
  const int idx = blockIdx.x * 256 + threadIdx.x;
  if (idx < 384 * 128) {
    const int c = idx >> 7, k = idx & 127;
    wTq[idx] = f2bf(qkv_w[k * 384 + c]);
  } else {
    const int i2 = idx - 384 * 128;
    const int c = i2 >> 7, k = i2 & 127;
    wTo[i2] = f2bf(out_w[k * 128 + c]);
  }
}

// ---------------------------------------------------------------------------
// K1: fused LayerNorm + QKV projection (MFMA), LDS-staged coalesced epilogue.
// Block = 256 (4 waves) handles 16 atoms. Wave w -> cols [w*96, w*96+96).
// so[atom][0..127] = q channels, so[atom][128..383] = interleaved {k,v}.
// ---------------------------------------------------------------------------
__global__ __launch_bounds__(256) void k_ln_qkv(
    const float* __restrict__ node, const unsigned short* __restrict__ wTq,
    const float* __restrict__ bias, const float* __restrict__ g,
    const float* __restrict__ beta, float* __restrict__ qarr,
    float* __restrict__ kvarr)
{
  __shared__ float hpad[16][132];
  __shared__ float so[16][388];
  const int a0 = blockIdx.x * 16;
  const int tid = threadIdx.x;
  const int wid = tid >> 6;
  const int lane = tid & 63;

  // phase 1: LayerNorm (wave `wid` does atoms wid*4 .. +3)
  for (int j = 0; j < 4; ++j) {
    const int a = wid * 4 + j;
    const float x0 = node[(size_t)(a0 + a) * DIM + lane];
    const float x1 = node[(size_t)(a0 + a) * DIM + 64 + lane];
    float s = x0 + x1;
    #pragma unroll
    for (int m = 1; m < 64; m <<= 1) s += __shfl_xor(s, m);
    const float mu = s * (1.0f / 128.0f);
    const float d0 = x0 - mu, d1 = x1 - mu;
    float v = d0 * d0 + d1 * d1;
    #pragma unroll
    for (int m = 1; m < 64; m <<= 1) v += __shfl_xor(v, m);
    const float rs = rsqrtf(v * (1.0f / 128.0f) + LN_EPS);
    hpad[a][lane]      = d0 * rs * g[lane]      + beta[lane];
    hpad[a][64 + lane] = d1 * rs * g[64 + lane] + beta[64 + lane];
  }
  __syncthreads();

  // phase 2: MFMA
  const int lrow = lane & 15;
  const int lquad = lane >> 4;
  const int colbase = wid * 96;

  s16x8 afrag[4];
  #pragma unroll
  for (int ks = 0; ks < 4; ++ks) {
    const int koff = ks * 32 + lquad * 8;
    const float4 p0 = *reinterpret_cast<const float4*>(&hpad[lrow][koff]);
    const float4 p1 = *reinterpret_cast<const float4*>(&hpad[lrow][koff + 4]);
    s16x8 af;
    af[0] = (short)f2bf(p0.x); af[1] = (short)f2bf(p0.y);
    af[2] = (short)f2bf(p0.z); af[3] = (short)f2bf(p0.w);
    af[4] = (short)f2bf(p1.x); af[5] = (short)f2bf(p1.y);
    af[6] = (short)f2bf(p1.z); af[7] = (short)f2bf(p1.w);
    afrag[ks] = af;
  }

  f32x4 acc[6];
  #pragma unroll
  for (int t = 0; t < 6; ++t) acc[t] = (f32x4){0.f, 0.f, 0.f, 0.f};

  #pragma unroll
  for (int t = 0; t < 6; ++t) {
    const int cg = colbase + t * 16 + lrow;
    #pragma unroll
    for (int ks = 0; ks < 4; ++ks) {
      const s16x8 bf = *reinterpret_cast<const s16x8*>(
          &wTq[(size_t)cg * 128 + ks * 32 + lquad * 8]);
      acc[t] = __builtin_amdgcn_mfma_f32_16x16x32_bf16(afrag[ks], bf, acc[t], 0, 0, 0);
    }
  }

  // epilogue: stage into LDS in the q/kv split layout
  #pragma unroll
  for (int t = 0; t < 6; ++t) {
    const int cg = colbase + t * 16 + lrow;
    const float bz = bias[cg];
    const int hj = cg / 24;
    const int off = cg - hj * 24;
    int moff;
    if (off < 8)       moff = hj * 8 + off;                 // q
    else if (off < 16) moff = 128 + (hj * 8 + off - 8) * 2; // k
    else               moff = 128 + (hj * 8 + off - 16) * 2 + 1; // v
    #pragma unroll
    for (int r = 0; r < 4; ++r)
      so[lquad * 4 + r][moff] = acc[t][r] + bz;
  }
  __syncthreads();

  // coalesced float4 stores: 96 float4 per atom row (32 q + 64 kv)
  f32x4* q4  = (f32x4*)qarr;
  f32x4* kv4 = (f32x4*)kvarr;
  #pragma unroll
  for (int kk = 0; kk < 6; ++kk) {
    const int idx4 = tid + kk * 256;     // 0..1535
    const int rowi = idx4 / 96;
    const int c4 = idx4 - rowi * 96;
    const f32x4 val = *reinterpret_cast<const f32x4*>(&so[rowi][c4 * 4]);
    if (c4 < 32) q4[(size_t)(a0 + rowi) * 32 + c4] = val;
    else         kv4[(size_t)(a0 + rowi) * 64 + (c4 - 32)] = val;
  }
}

// ---------------------------------------------------------------------------
// CSR build: histogram -> parallel 3-phase scan -> scatter permutation
// ---------------------------------------------------------------------------
__global__ __launch_bounds__(256) void k_hist(const int* __restrict__ row,
                                              int* __restrict__ cnt) {
  const int e = blockIdx.x * 256 + threadIdx.x;
  if (e < NEDGES) atomicAdd(&cnt[row[e]], 1);
}

#define SCAN_NB 196  // ceil(50000/256)

__global__ __launch_bounds__(256) void k_scan1(const int* __restrict__ cnt,
                                               int* __restrict__ locx,
                                               int* __restrict__ psum) {
  __shared__ int sh[256];
  const int tid = threadIdx.x;
  const int i = blockIdx.x * 256 + tid;
  const int v = (i < NATOMS) ? cnt[i] : 0;
  sh[tid] = v;
  __syncthreads();
  #pragma unroll
  for (int off = 1; off < 256; off <<= 1) {
    const int cur = sh[tid];
    const int add = (tid >= off) ? sh[tid - off] : 0;
    __syncthreads();
    sh[tid] = cur + add;
    __syncthreads();
  }
  if (i < NATOMS) locx[i] = sh[tid] - v;  // exclusive
  if (tid == 255) psum[blockIdx.x] = sh[255];
}

__global__ __launch_bounds__(256) void k_scan2(const int* __restrict__ psum,
                                               int* __restrict__ poff,
                                               int* __restrict__ base) {
  __shared__ int sh[256];
  const int tid = threadIdx.x;
  const int v = (tid < SCAN_NB) ? psum[tid] : 0;
  sh[tid] = v;
  __syncthreads();
  #pragma unroll
  for (int off = 1; off < 256; off <<= 1) {
    const int cur = sh[tid];
    const int add = (tid >= off) ? sh[tid - off] : 0;
    __syncthreads();
    sh[tid] = cur + add;
    __syncthreads();
  }
  if (tid < SCAN_NB) poff[tid] = sh[tid] - v;  // exclusive block offset
  if (tid == 255) base[NATOMS] = sh[255];      // total = NEDGES
}

__global__ __launch_bounds__(256) void k_scan3(const int* __restrict__ locx,
                                               const int* __restrict__ poff,
                                               int* __restrict__ base,
                                               int* __restrict__ cursor) {
  const int i = blockIdx.x * 256 + threadIdx.x;
  if (i < NATOMS) {
    const int b = locx[i] + poff[blockIdx.x];
    base[i] = b;
    cursor[i] = b;
  }
}

__global__ __launch_bounds__(256) void k_scatter(const int* __restrict__ row,
                                                 int* __restrict__ cursor,
                                                 int* __restrict__ perm) {
  const int e = blockIdx.x * 256 + threadIdx.x;
  if (e < NEDGES) {
    const int p = atomicAdd(&cursor[row[e]], 1);
    perm[p] = e;
  }
}

// ---------------------------------------------------------------------------
// K2: per-atom edge accumulation, software-pipelined.
// 64 threads (1 wave) per atom; thread t owns channels 2t, 2t+1.
// kv is float4 {k(2t),v(2t),k(2t+1),v(2t+1)} at index atom*64+t.
// Dot over a head (8 ch, threads 4h..4h+3): 2 local fma + 2 shuffles.
// Unroll-2 over edges, data 1 pair ahead, indices 2 pairs ahead (scalar path,
// valid because each wave maps to exactly one atom).
// ---------------------------------------------------------------------------
__global__ __launch_bounds__(256) void k_edge_csr(
    const float* __restrict__ qarr, const f32x4* __restrict__ kv,
    const float2* __restrict__ ef2, const float* __restrict__ evec,
    const float* __restrict__ radial, const int* __restrict__ col,
    const int* __restrict__ base, const int* __restrict__ perm,
    unsigned int* __restrict__ mfeatw, float* __restrict__ outvec)
{
  const int tid = threadIdx.x;
  const int a = blockIdx.x * 4 + (tid >> 6);
  const int t = tid & 63;

  const int beg = base[a];
  const int end = base[a + 1];

  float f0 = 0.f, f1 = 0.f;
  float va0 = 0.f, va1 = 0.f, vb0 = 0.f, vb1 = 0.f, vc0 = 0.f, vc1 = 0.f;

  if (beg < end) {
    const float2 q2 = *reinterpret_cast<const float2*>(qarr + (size_t)a * 128 + 2 * t);
    const int last = end - 1;

    int nE0, nC0, nE1, nC1;
    f32x4 kv0, kv1;
    float2 fe0, fe1;
    float r0, r1;
    float a00, a01, a02, b00, b01, b02;

    // idx pair 0
    {
      const int i1 = (beg + 1 <= last) ? beg + 1 : last;
      nE0 = __builtin_amdgcn_readfirstlane(perm[beg]);
      nE1 = __builtin_amdgcn_readfirstlane(perm[i1]);
      nC0 = __builtin_amdgcn_readfirstlane(col[nE0]);
      nC1 = __builtin_amdgcn_readfirstlane(col[nE1]);
    }
    // data pair 0
    kv0 = kv[(size_t)nC0 * 64 + t];
    kv1 = kv[(size_t)nC1 * 64 + t];
    fe0 = ef2[(size_t)nE0 * 64 + t];
    fe1 = ef2[(size_t)nE1 * 64 + t];
    r0 = radial[nE0]; r1 = radial[nE1];
    a00 = evec[(size_t)nE0 * 3]; a01 = evec[(size_t)nE0 * 3 + 1]; a02 = evec[(size_t)nE0 * 3 + 2];
    b00 = evec[(size_t)nE1 * 3]; b01 = evec[(size_t)nE1 * 3 + 1]; b02 = evec[(size_t)nE1 * 3 + 2];
    // idx pair 1
    {
      const int j0 = (beg + 2 <= last) ? beg + 2 : last;
      const int j1 = (beg + 3 <= last) ? beg + 3 : last;
      nE0 = __builtin_amdgcn_readfirstlane(perm[j0]);
      nE1 = __builtin_amdgcn_readfirstlane(perm[j1]);
      nC0 = __builtin_amdgcn_readfirstlane(col[nE0]);
      nC1 = __builtin_amdgcn_readfirstlane(col[nE1]);
    }

    for (int i = beg; i < end; i += 2) {
      f32x4 ukv0 = kv0, ukv1 = kv1;
      const float2 uf0 = fe0, uf1 = fe1;
      const float ur0 = r0, ur1 = r1;
      const float ua0 = a00, ua1 = a01, ua2 = a02;
      const float ub0 = b00, ub1 = b01, ub2 = b02;

      if (i + 2 < end) {
        kv0 = kv[(size_t)nC0 * 64 + t];
        kv1 = kv[(size_t)nC1 * 64 + t];
        fe0 = ef2[(size_t)nE0 * 64 + t];
        fe1 = ef2[(size_t)nE1 * 64 + t];
        r0 = radial[nE0]; r1 = radial[nE1];
        a00 = evec[(size_t)nE0 * 3]; a01 = evec[(size_t)nE0 * 3 + 1]; a02 = evec[(size_t)nE0 * 3 + 2];
        b00 = evec[(size_t)nE1 * 3]; b01 = evec[(size_t)nE1 * 3 + 1]; b02 = evec[(size_t)nE1 * 3 + 2];
        const int j0 = (i + 4 <= last) ? i + 4 : last;
        const int j1 = (i + 5 <= last) ? i + 5 : last;
        nE0 = __builtin_amdgcn_readfirstlane(perm[j0]);
        nE1 = __builtin_amdgcn_readfirstlane(perm[j1]);
        nC0 = __builtin_amdgcn_readfirstlane(col[nE0]);
        nC1 = __builtin_amdgcn_readfirstlane(col[nE1]);
      }

      // mask invalid second edge (zero kv kills dot and products)
      const float m1 = (i + 1 < end) ? 1.f : 0.f;
      ukv1 *= m1;

      // dot over head: 2 local channels + xor-1 + xor-2
      float p0 = q2.x * ukv0[0];
      p0 = fmaf(q2.y, ukv0[2], p0);
      p0 += __shfl_xor(p0, 1); p0 += __shfl_xor(p0, 2);
      float p1 = q2.x * ukv1[0];
      p1 = fmaf(q2.y, ukv1[2], p1);
      p1 += __shfl_xor(p1, 1); p1 += __shfl_xor(p1, 2);

      const float at0 = gelu_fast(p0) * ur0;
      const float at1 = gelu_fast(p1) * ur1;

      f0 = fmaf(ukv0[1] * uf0.x, at0, f0);
      f1 = fmaf(ukv0[3] * uf0.y, at0, f1);
      f0 = fmaf(ukv1[1] * uf1.x, at1, f0);
      f1 = fmaf(ukv1[3] * uf1.y, at1, f1);

      va0 = fmaf(ukv0[1], ua0, fmaf(ukv1[1], ub0, va0));
      va1 = fmaf(ukv0[3], ua0, fmaf(ukv1[3], ub0, va1));
      vb0 = fmaf(ukv0[1], ua1, fmaf(ukv1[1], ub1, vb0));
      vb1 = fmaf(ukv0[3], ua1, fmaf(ukv1[3], ub1, vb1));
      vc0 = fmaf(ukv0[1], ua2, fmaf(ukv1[1], ub2, vc0));
      vc1 = fmaf(ukv0[3], ua2, fmaf(ukv1[3], ub2, vc1));
    }
  }

  // stores: 2 channels per thread
  mfeatw[(size_t)a * 64 + t] =
      (unsigned)f2bf(f0) | ((unsigned)f2bf(f1) << 16);
  float* ov = outvec + (size_t)a * 384 + 2 * t;
  *reinterpret_cast<float2*>(ov)       = make_float2(va0, va1);
  *reinterpret_cast<float2*>(ov + 128) = make_float2(vb0, vb1);
  *reinterpret_cast<float2*>(ov + 256) = make_float2(vc0, vc1);
}

// ---------------------------------------------------------------------------
// K3: delta_node_feat = m_feat(bf16) @ out_wT(bf16) + out_b via MFMA,
// LDS-staged coalesced epilogue.
// ---------------------------------------------------------------------------
__global__ __launch_bounds__(256) void k_out(
    const unsigned short* __restrict__ mfeatb,
    const unsigned short* __restrict__ wTo,
    const float* __restrict__ bias, float* __restrict__ out)
{
  __shared__ float so[16][132];
  const int a0 = blockIdx.x * 16;
  const int tid = threadIdx.x;
  const int wid = tid >> 6;
  const int lane = tid & 63;
  const int lrow = lane & 15;
  const int lquad = lane >> 4;

  s16x8 afrag[4];
  #pragma unroll
  for (int ks = 0; ks < 4; ++ks)
    afrag[ks] = *reinterpret_cast<const s16x8*>(
        &mfeatb[(size_t)(a0 + lrow) * 128 + ks * 32 + lquad * 8]);

  f32x4 acc[2];
  acc[0] = (f32x4){0.f, 0.f, 0.f, 0.f};
  acc[1] = (f32x4){0.f, 0.f, 0.f, 0.f};

  #pragma unroll
  for (int t = 0; t < 2; ++t) {
    const int cg = wid * 32 + t * 16 + lrow;
    #pragma unroll
    for (int ks = 0; ks < 4; ++ks) {
      const s16x8 bf = *reinterpret_cast<const s16x8*>(
          &wTo[(size_t)cg * 128 + ks * 32 + lquad * 8]);
      acc[t] = __builtin_amdgcn_mfma_f32_16x16x32_bf16(afrag[ks], bf, acc[t], 0, 0, 0);
    }
  }

  #pragma unroll
  for (int t = 0; t < 2; ++t) {
    const int cg = wid * 32 + t * 16 + lrow;
    const float bz = bias[cg];
    #pragma unroll
    for (int r = 0; r < 4; ++r)
      so[lquad * 4 + r][cg] = acc[t][r] + bz;
  }
  __syncthreads();

  f32x4* out4 = (f32x4*)out;
  #pragma unroll
  for (int kk = 0; kk < 2; ++kk) {
    const int idx4 = tid + kk * 256;   // 0..511
    const int rowi = idx4 >> 5;
    const int c4 = idx4 & 31;
    out4[(size_t)(a0 + rowi) * 32 + c4] =
        *reinterpret_cast<const f32x4*>(&so[rowi][c4 * 4]);
  }
}

extern "C" void kernel_launch(void* const* d_in, const int* in_sizes, int n_in,
                              void* d_out, int out_size, void* d_ws, size_t ws_size,
                              hipStream_t stream) {
  const float* node_feat = (const float*)d_in[0];
  const float* edge_feat = (const float*)d_in[1];
  const float* edge_vec  = (const float*)d_in[2];
  const float* radial    = (const float*)d_in[3];
  const float* qkv_w     = (const float*)d_in[4];
  const float* qkv_b     = (const float*)d_in[5];
  const float* out_w     = (const float*)d_in[6];
  const float* out_b     = (const float*)d_in[7];
  const float* ln_g      = (const float*)d_in[8];
  const float* ln_b      = (const float*)d_in[9];
  const int*   row       = (const int*)d_in[10];
  const int*   col       = (const int*)d_in[11];

  float* out      = (float*)d_out;
  float* out_feat = out;                           // [50000][128]
  float* out_vec  = out + (size_t)NATOMS * DIM;    // [50000][3][128]

  // workspace layout (16B-aligned sections)
  float* qarr   = (float*)d_ws;                                 // 50000*128 f32
  float* kvarr  = qarr + (size_t)NATOMS * 128;                  // 50000*256 f32
  unsigned short* mfeatb = (unsigned short*)(kvarr + (size_t)NATOMS * 256); // 50000*128 bf16
  unsigned short* wTq = mfeatb + (size_t)NATOMS * 128;          // 384*128 bf16
  unsigned short* wTo = wTq + 384 * 128;                        // 128*128 bf16
  int* cnt    = (int*)(wTo + 128 * 128);                        // 50000
  int* base   = cnt + NATOMS;                                   // 50001
  int* cursor = base + NATOMS + 1;                              // 50000
  int* perm   = cursor + NATOMS;                                // 400000
  int* locx   = perm + NEDGES;                                  // 50000
  int* psum   = locx + NATOMS;                                  // 256
  int* poff   = psum + 256;                                     // 256

  hipMemsetAsync(cnt, 0, NATOMS * sizeof(int), stream);

  k_convert_w<<<(384 * 128 + 128 * 128) / 256, 256, 0, stream>>>(qkv_w, out_w, wTq, wTo);

  const int eb = (NEDGES + 255) / 256;
  k_hist<<<eb, 256, 0, stream>>>(row, cnt);
  k_scan1<<<SCAN_NB, 256, 0, stream>>>(cnt, locx, psum);
  k_scan2<<<1, 256, 0, stream>>>(psum, poff, base);
  k_scan3<<<SCAN_NB, 256, 0, stream>>>(locx, poff, base, cursor);
  k_scatter<<<eb, 256, 0, stream>>>(row, cursor, perm);

  k_ln_qkv<<<NATOMS / 16, 256, 0, stream>>>(node_feat, wTq, qkv_b, ln_g, ln_b,
                                            qarr, kvarr);

  k_edge_csr<<<(NATOMS + 3) / 4, 256, 0, stream>>>(
      qarr, (const f32x4*)kvarr, (const float2*)edge_feat, edge_vec, radial,
      col, base, perm, (unsigned int*)mfeatb, out_vec);

  k_out<<<NATOMS / 16, 256, 0, stream>>>(mfeatb, wTo, out_b, out_feat);
}